// Round 3
// baseline (381.004 us; speedup 1.0000x reference)
//
#include <hip/hip_runtime.h>

typedef unsigned short u16;
typedef unsigned int u32;
typedef __attribute__((ext_vector_type(8))) short short8;
typedef __attribute__((ext_vector_type(4))) float f32x4;

// ---------------- helpers ----------------
__device__ __forceinline__ u16 f2bf(float f) {
    unsigned int u = __float_as_uint(f);
    u += 0x7fffu + ((u >> 16) & 1u);   // round-to-nearest-even
    return (u16)(u >> 16);
}

__device__ __forceinline__ u32 pack_trunc(float a, float b) {
    return __builtin_amdgcn_perm(__float_as_uint(b), __float_as_uint(a), 0x07060302u);
}

// async global->LDS, 16B per lane. LDS dest = wave-uniform base + lane*16.
__device__ __forceinline__ void gload16(const u16* g, const u16* l) {
    __builtin_amdgcn_global_load_lds(
        (const __attribute__((address_space(1))) unsigned int*)g,
        (__attribute__((address_space(3))) unsigned int*)l, 16, 0, 0);
}

// ---------------- fused cast fp32 -> bf16 (all 7 tensors, one launch) ----------------
__global__ __launch_bounds__(256) void cast_all(const float* __restrict__ k,
                                                const float* __restrict__ q,
                                                const float* __restrict__ v,
                                                const float* __restrict__ wk,
                                                const float* __restrict__ wq,
                                                const float* __restrict__ wv,
                                                const float* __restrict__ wo,
                                                u16* __restrict__ Xk, u16* __restrict__ Xq,
                                                u16* __restrict__ Xv, u16* __restrict__ Wk,
                                                u16* __restrict__ Wq, u16* __restrict__ Wv,
                                                u16* __restrict__ Wo) {
    size_t i = ((size_t)blockIdx.x * 256 + threadIdx.x) * 8;
    const float* src; u16* dst; size_t off;
    if (i < 25165824) {                       // 3 x 2^23 activations
        int r = (int)(i >> 23); off = i & 8388607;
        src = r == 0 ? k : (r == 1 ? q : v);
        dst = r == 0 ? Xk : (r == 1 ? Xq : Xv);
    } else {                                  // 4 x 2^20 weights
        size_t j = i - 25165824;
        int r = (int)(j >> 20); off = j & 1048575;
        src = r == 0 ? wk : (r == 1 ? wq : (r == 2 ? wv : wo));
        dst = r == 0 ? Wk : (r == 1 ? Wq : (r == 2 ? Wv : Wo));
    }
    float4 a = *(const float4*)(src + off);
    float4 b = *(const float4*)(src + off + 4);
    union { u16 h[8]; uint4 u; } r8;
    r8.h[0] = f2bf(a.x); r8.h[1] = f2bf(a.y); r8.h[2] = f2bf(a.z); r8.h[3] = f2bf(a.w);
    r8.h[4] = f2bf(b.x); r8.h[5] = f2bf(b.y); r8.h[6] = f2bf(b.z); r8.h[7] = f2bf(b.w);
    *(uint4*)(dst + off) = r8.u;
}

// =====================================================================================
// v4 GEMM core: m201 8-phase template, BM=BN=256, BK=64, 8 waves (2M x 4N),
// per-wave C = 128x64 = acc[8][4]. LDS 128KB = 2dbuf x (A 256x64 + B 256x64) bf16,
// each tensor-buffer split as [half(128rows)][row][slot'] with slot' = slot ^ (row&7)
// (bank swizzle, PMC-verified 0 conflicts; staged via inverse-permuted global source).
//
// Per K-tile, 4 fine phases (quadrants of the per-wave 128x64):
//  p0: ds_read A[mh0] (8xb128) + B[nh0] (4); STAGE A-halves of tile t+1 (4 gloads);
//      barrier; lgkmcnt(0); setprio(1); 16 MFMA Q(0,0); setprio(0); barrier
//  p1: ds_read B[nh1] (4); STAGE B-halves t+1 (4 gloads); ...; MFMA Q(0,1); barrier
//  p2: ds_read A[mh1] (8); ...; MFMA Q(1,1); barrier
//  p3: MFMA Q(1,0) [reuses b0 regs]; s_waitcnt vmcnt(0) [stages ~2.5-3.5 phases old
//      => near-free]; barrier  -> next tile
// 24 ds_read_b128 per wave per K-tile feed 64 MFMA = 384 B/MFMA (m201's proven ratio).
// =====================================================================================

#define RD_A(bufp, mh, mf, kh) \
  (*(const short8*)((bufp) + wm * 8192 + ((mh) * 64 + (mf) * 16 + l16) * 64 + \
                    ((((kh) * 4 + quad)) ^ swz) * 8))
#define RD_B(bufp, nh, nf, kh) \
  (*(const short8*)((bufp) + (wn >> 1) * 8192 + \
                    ((wn & 1) * 64 + (nh) * 32 + (nf) * 16 + l16) * 64 + \
                    ((((kh) * 4 + quad)) ^ swz) * 8))

#define STAGE_A(bufn, kt) { \
    u16* d = sAr + (bufn) * 16384 + tid * 8; \
    const u16* g = gA + (kt); \
    gload16(g,          d); \
    gload16(g + 65536,  d + 4096); \
    gload16(g + 131072, d + 8192); \
    gload16(g + 196608, d + 12288); }

#define STAGE_B(bufn, kt) { \
    u16* d = sBr + (bufn) * 16384 + tid * 8; \
    const u16* g = gB + (kt); \
    gload16(g,          d); \
    gload16(g + 65536,  d + 4096); \
    gload16(g + 131072, d + 8192); \
    gload16(g + 196608, d + 12288); }

#define MFMA_Q(mh, nh, A, B) \
  _Pragma("unroll") for (int mf = 0; mf < 4; mf++) \
  _Pragma("unroll") for (int nf = 0; nf < 2; nf++) \
  _Pragma("unroll") for (int kh = 0; kh < 2; kh++) \
    acc[(mh) * 4 + mf][(nh) * 2 + nf] = __builtin_amdgcn_mfma_f32_16x16x32_bf16( \
        A[mf][kh], B[nf][kh], acc[(mh) * 4 + mf][(nh) * 2 + nf], 0, 0, 0);

#define PHASE_SYNC() \
    __builtin_amdgcn_s_barrier(); \
    asm volatile("s_waitcnt lgkmcnt(0)" ::: "memory"); \
    __builtin_amdgcn_sched_barrier(0);

#define GEMM256_PIPELINE(X_, W_) \
  const int sRow = tid >> 3; \
  const int sColSw = ((tid & 7) ^ (sRow & 7)) * 8; \
  const u16* gA = (X_) + (size_t)(i0 + sRow) * 1024 + sColSw; \
  const u16* gB = (W_) + (size_t)(j0 + sRow) * 1024 + sColSw; \
  const int swz = l16 & 7; \
  STAGE_A(0, 0); STAGE_B(0, 0); \
  asm volatile("s_waitcnt vmcnt(0)" ::: "memory"); \
  __builtin_amdgcn_s_barrier(); \
  _Pragma("unroll 1") \
  for (int t = 0; t < 16; t++) { \
    const int bc = t & 1; const int bn = bc ^ 1; const int ktn = (t + 1) * 64; \
    const u16* bufA = sAr + bc * 16384; \
    const u16* bufB = sBr + bc * 16384; \
    short8 a[4][2], b0[2][2], b1[2][2]; \
    /* ---- phase 0 ---- */ \
    _Pragma("unroll") for (int mf = 0; mf < 4; mf++) \
      _Pragma("unroll") for (int kh = 0; kh < 2; kh++) a[mf][kh] = RD_A(bufA, 0, mf, kh); \
    _Pragma("unroll") for (int nf = 0; nf < 2; nf++) \
      _Pragma("unroll") for (int kh = 0; kh < 2; kh++) b0[nf][kh] = RD_B(bufB, 0, nf, kh); \
    if (t < 15) { STAGE_A(bn, ktn); } \
    PHASE_SYNC(); \
    __builtin_amdgcn_s_setprio(1); MFMA_Q(0, 0, a, b0); __builtin_amdgcn_s_setprio(0); \
    __builtin_amdgcn_s_barrier(); \
    /* ---- phase 1 ---- */ \
    _Pragma("unroll") for (int nf = 0; nf < 2; nf++) \
      _Pragma("unroll") for (int kh = 0; kh < 2; kh++) b1[nf][kh] = RD_B(bufB, 1, nf, kh); \
    if (t < 15) { STAGE_B(bn, ktn); } \
    PHASE_SYNC(); \
    __builtin_amdgcn_s_setprio(1); MFMA_Q(0, 1, a, b1); __builtin_amdgcn_s_setprio(0); \
    __builtin_amdgcn_s_barrier(); \
    /* ---- phase 2 ---- */ \
    _Pragma("unroll") for (int mf = 0; mf < 4; mf++) \
      _Pragma("unroll") for (int kh = 0; kh < 2; kh++) a[mf][kh] = RD_A(bufA, 1, mf, kh); \
    PHASE_SYNC(); \
    __builtin_amdgcn_s_setprio(1); MFMA_Q(1, 1, a, b1); __builtin_amdgcn_s_setprio(0); \
    __builtin_amdgcn_s_barrier(); \
    /* ---- phase 3 ---- */ \
    __builtin_amdgcn_s_setprio(1); MFMA_Q(1, 0, a, b0); __builtin_amdgcn_s_setprio(0); \
    asm volatile("s_waitcnt vmcnt(0)" ::: "memory"); \
    __builtin_amdgcn_s_barrier(); \
  }

// ---------------- batched QKV GEMM: 384 blocks, XCD-chunked (48/XCD) ------------------
__global__ __launch_bounds__(512, 2) void gemm_qkv(const u16* __restrict__ Xk,
                                                   const u16* __restrict__ Xq,
                                                   const u16* __restrict__ Xv,
                                                   const u16* __restrict__ Wk,
                                                   const u16* __restrict__ Wq,
                                                   const u16* __restrict__ Wv,
                                                   const float* __restrict__ bK,
                                                   const float* __restrict__ bQ,
                                                   const float* __restrict__ bV,
                                                   u16* __restrict__ Kbh,
                                                   u16* __restrict__ Qbh,
                                                   u16* __restrict__ Vtg,
                                                   float kscale) {
    extern __shared__ __align__(16) u16 smem[];
    u16* sAr = smem;            // 2 bufs x 16384 u16
    u16* sBr = smem + 32768;    // 2 bufs x 16384 u16
    // bijective XCD chunking: 384 = 8 XCD * 48; j varies fastest within a chunk.
    const int f  = blockIdx.x;
    const int wg = (f & 7) * 48 + (f >> 3);
    const int z  = wg >> 7;          // 3 z x 128 tiles (32 i x 4 j)
    const int r7 = wg & 127;
    const int i0 = (r7 >> 2) * 256;
    const int j0 = (r7 & 3) * 256;

    const u16* X = z == 0 ? Xk : (z == 1 ? Xq : Xv);
    const u16* W = z == 0 ? Wk : (z == 1 ? Wq : Wv);
    const float* bias = z == 0 ? bK : (z == 1 ? bQ : bV);
    u16* out = z == 0 ? Kbh : (z == 1 ? Qbh : Vtg);
    const float scale = z == 0 ? kscale : 1.0f;

    const int tid  = threadIdx.x;
    const int wave = tid >> 6, lane = tid & 63;
    const int quad = lane >> 4, l16 = lane & 15;
    const int wm = wave >> 2, wn = wave & 3;   // 2M x 4N

    f32x4 acc[8][4];
    #pragma unroll
    for (int m = 0; m < 8; m++)
        #pragma unroll
        for (int n = 0; n < 4; n++) acc[m][n] = (f32x4){0.f, 0.f, 0.f, 0.f};

    GEMM256_PIPELINE(X, W)

    #pragma unroll
    for (int m = 0; m < 8; m++) {
        #pragma unroll
        for (int n = 0; n < 4; n++) {
            int j = j0 + wn * 64 + n * 16 + l16;
            float bj = bias[j];
            #pragma unroll
            for (int r = 0; r < 4; r++) {
                int i = i0 + wm * 128 + m * 16 + quad * 4 + r;
                float v = (acc[m][n][r] + bj) * scale;
                int b = i >> 11, tt = i & 2047;
                int h = j >> 6,  dd = j & 63;
                size_t idx;
                if (z == 2) idx = (((size_t)(b * 16 + h)) * 64 + dd) * 2048 + tt;
                else        idx = (((size_t)(b * 16 + h)) * 2048 + tt) * 64 + dd;
                out[idx] = f2bf(v);
            }
        }
    }
}

// ---------------- output GEMM: 128 blocks, XCD-chunked (16/XCD) -----------------------
__global__ __launch_bounds__(512, 2) void gemm_out(const u16* __restrict__ X,
                                                   const u16* __restrict__ W,
                                                   const float* __restrict__ bias,
                                                   float* __restrict__ out) {
    extern __shared__ __align__(16) u16 smem[];
    u16* sAr = smem;
    u16* sBr = smem + 32768;
    const int f  = blockIdx.x;
    const int wg = (f & 7) * 16 + (f >> 3);
    const int i0 = (wg >> 2) * 256;
    const int j0 = (wg & 3) * 256;

    const int tid  = threadIdx.x;
    const int wave = tid >> 6, lane = tid & 63;
    const int quad = lane >> 4, l16 = lane & 15;
    const int wm = wave >> 2, wn = wave & 3;

    f32x4 acc[8][4];
    #pragma unroll
    for (int m = 0; m < 8; m++)
        #pragma unroll
        for (int n = 0; n < 4; n++) acc[m][n] = (f32x4){0.f, 0.f, 0.f, 0.f};

    GEMM256_PIPELINE(X, W)

    #pragma unroll
    for (int m = 0; m < 8; m++) {
        #pragma unroll
        for (int n = 0; n < 4; n++) {
            int j = j0 + wn * 64 + n * 16 + l16;
            float bj = bias[j];
            #pragma unroll
            for (int r = 0; r < 4; r++) {
                int i = i0 + wm * 128 + m * 16 + quad * 4 + r;
                out[(size_t)i * 1024 + j] = acc[m][n][r] + bj;
            }
        }
    }
}

// ---------------- flash attention v4 + XCD swizzle (512 blocks) ----------------
#define QST 72   // LDS row stride in u16

__global__ __launch_bounds__(256, 2) void attn_kernel(const u16* __restrict__ Kbh,
                                                      const u16* __restrict__ Qbh,
                                                      const u16* __restrict__ Vtg,
                                                      u16* __restrict__ ctx) {
    __shared__ u16 sQ[64 * QST];             // [s_local][dk]
    __shared__ u16 sVt[64 * QST];            // [dk][s_local]
    __shared__ u16 sP[4 * 2 * 16 * QST];     // [wave][buf][t16][s64]
    const int f = blockIdx.x;
    const int bh = (f & 7) | ((f >> 6) << 3);
    const int tx = (f >> 3) & 7;
    const int tid  = threadIdx.x;
    const int wave = tid >> 6, lane = tid & 63;
    const int quad = lane >> 4, l16 = lane & 15;
    const int t0 = tx * 256;
    const int tw = t0 + wave * 64;
    const size_t base = (size_t)bh * 2048 * 64;

    short8 bk[4][2];
    #pragma unroll
    for (int g = 0; g < 4; g++) {
        const u16* kr = Kbh + base + (size_t)(tw + g * 16 + l16) * 64 + quad * 8;
        bk[g][0] = *(const short8*)kr;
        bk[g][1] = *(const short8*)(kr + 32);
    }
    const short8 ones = {0x3F80, 0x3F80, 0x3F80, 0x3F80, 0x3F80, 0x3F80, 0x3F80, 0x3F80};

    f32x4 accO[4][4];
    #pragma unroll
    for (int g = 0; g < 4; g++)
        #pragma unroll
        for (int dt = 0; dt < 4; dt++) accO[g][dt] = (f32x4){0.f, 0.f, 0.f, 0.f};
    f32x4 accL[4];
    #pragma unroll
    for (int g = 0; g < 4; g++) accL[g] = (f32x4){0.f, 0.f, 0.f, 0.f};

    const int srow = tid >> 2, seg = tid & 3;
    u16* sPw = sP + wave * 2 * 16 * QST;

    for (int s0 = 0; s0 < 2048; s0 += 64) {
        __syncthreads();
        {   // stage Q chunk [s][dk]
            const uint4* gq = (const uint4*)(Qbh + base + (size_t)(s0 + srow) * 64 + seg * 16);
            uint4 q0 = gq[0], q1 = gq[1];
            *(uint4*)&sQ[srow * QST + seg * 16]     = q0;
            *(uint4*)&sQ[srow * QST + seg * 16 + 8] = q1;
        }
        {   // stage V^T chunk [dk][s]
            const uint4* gv = (const uint4*)(Vtg + ((size_t)bh * 64 + srow) * 2048 + s0 + seg * 16);
            uint4 v0 = gv[0], v1 = gv[1];
            *(uint4*)&sVt[srow * QST + seg * 16]     = v0;
            *(uint4*)&sVt[srow * QST + seg * 16 + 8] = v1;
        }
        __syncthreads();

        short8 aq[4][2], av[2][4];
        #pragma unroll
        for (int nt = 0; nt < 4; nt++) {
            aq[nt][0] = *(const short8*)&sQ[(nt * 16 + l16) * QST + quad * 8];
            aq[nt][1] = *(const short8*)&sQ[(nt * 16 + l16) * QST + 32 + quad * 8];
        }
        #pragma unroll
        for (int kk = 0; kk < 2; kk++)
            #pragma unroll
            for (int dt = 0; dt < 4; dt++)
                av[kk][dt] = *(const short8*)&sVt[(dt * 16 + l16) * QST + kk * 32 + quad * 8];

        #pragma unroll
        for (int g = 0; g < 4; g++) {
            f32x4 aS[4];
            #pragma unroll
            for (int nt = 0; nt < 4; nt++) {
                f32x4 s = __builtin_amdgcn_mfma_f32_16x16x32_bf16(aq[nt][0], bk[g][0],
                            (f32x4){0.f, 0.f, 0.f, 0.f}, 0, 0, 0);
                aS[nt] = __builtin_amdgcn_mfma_f32_16x16x32_bf16(aq[nt][1], bk[g][1], s, 0, 0, 0);
            }
            u16* pb = sPw + (g & 1) * 16 * QST;
            #pragma unroll
            for (int nt = 0; nt < 4; nt++) {
                float p0 = __builtin_amdgcn_exp2f(aS[nt][0]);
                float p1 = __builtin_amdgcn_exp2f(aS[nt][1]);
                float p2 = __builtin_amdgcn_exp2f(aS[nt][2]);
                float p3 = __builtin_amdgcn_exp2f(aS[nt][3]);
                uint2 pk = { pack_trunc(p0, p1), pack_trunc(p2, p3) };
                *(uint2*)&pb[l16 * QST + nt * 16 + quad * 4] = pk;
            }
            #pragma unroll
            for (int kk = 0; kk < 2; kk++) {
                short8 bp = *(const short8*)&pb[l16 * QST + kk * 32 + quad * 8];
                accL[g] = __builtin_amdgcn_mfma_f32_16x16x32_bf16(ones, bp, accL[g], 0, 0, 0);
                #pragma unroll
                for (int dt = 0; dt < 4; dt++)
                    accO[g][dt] = __builtin_amdgcn_mfma_f32_16x16x32_bf16(av[kk][dt], bp, accO[g][dt], 0, 0, 0);
            }
        }
    }

    const int b = bh >> 4, h = bh & 15;
    #pragma unroll
    for (int g = 0; g < 4; g++) {
        float inv = 1.f / accL[g][0];
        int t = tw + g * 16 + l16;
        u16* orow = ctx + ((size_t)(b * 2048 + t)) * 1024 + h * 64;
        #pragma unroll
        for (int dt = 0; dt < 4; dt++) {
            union { u16 h4[4]; uint2 u; } o;
            #pragma unroll
            for (int r = 0; r < 4; r++) o.h4[r] = f2bf(accO[g][dt][r] * inv);
            *(uint2*)&orow[dt * 16 + quad * 4] = o.u;
        }
    }
}

// ---------------- launcher ----------------
extern "C" void kernel_launch(void* const* d_in, const int* in_sizes, int n_in,
                              void* d_out, int out_size, void* d_ws, size_t ws_size,
                              hipStream_t stream) {
    const float* keys    = (const float*)d_in[0];
    const float* queries = (const float*)d_in[1];
    const float* values  = (const float*)d_in[2];
    const float* WKb = (const float*)d_in[5];
    const float* WQb = (const float*)d_in[7];
    const float* WVb = (const float*)d_in[9];
    const float* WOb = (const float*)d_in[11];

    char* ws = (char*)d_ws;
    const size_t MB = 1 << 20;
    u16* Kbh = (u16*)(ws + 0 * MB);
    u16* Qbh = (u16*)(ws + 16 * MB);
    u16* Vtg = (u16*)(ws + 32 * MB);
    u16* Xk  = (u16*)(ws + 48 * MB);
    u16* Xq  = (u16*)(ws + 64 * MB);
    u16* Xv  = (u16*)(ws + 80 * MB);
    u16* Wk  = (u16*)(ws + 96 * MB);
    u16* Wq  = (u16*)(ws + 98 * MB);
    u16* Wv  = (u16*)(ws + 100 * MB);
    u16* Wo  = (u16*)(ws + 102 * MB);
    u16* ctx = (u16*)(ws + 48 * MB);   // aliases Xk (dead after QKV projection)

    // 128KB dynamic LDS per GEMM block: raise the cap once.
    static bool attr_done = false;
    if (!attr_done) {
        hipFuncSetAttribute((const void*)gemm_qkv,
                            hipFuncAttributeMaxDynamicSharedMemorySize, 131072);
        hipFuncSetAttribute((const void*)gemm_out,
                            hipFuncAttributeMaxDynamicSharedMemorySize, 131072);
        attr_done = true;
    }

    cast_all<<<14336, 256, 0, stream>>>(keys, queries, values,
                                        (const float*)d_in[4], (const float*)d_in[6],
                                        (const float*)d_in[8], (const float*)d_in[10],
                                        Xk, Xq, Xv, Wk, Wq, Wv, Wo);

    const float kscale = 1.4426950408889634f * 0.125f;  // log2(e)/sqrt(d_key)
    gemm_qkv<<<384, 512, 131072, stream>>>(Xk, Xq, Xv, Wk, Wq, Wv,
                                           WKb, WQb, WVb, Kbh, Qbh, Vtg, kscale);

    attn_kernel<<<512, 256, 0, stream>>>(Kbh, Qbh, Vtg, ctx);

    gemm_out<<<128, 512, 131072, stream>>>(ctx, Wo, WOb, (float*)d_out);
}

// Round 4
// 334.891 us; speedup vs baseline: 1.1377x; 1.1377x over previous
//
#include <hip/hip_runtime.h>

typedef unsigned short u16;
typedef unsigned int u32;
typedef __attribute__((ext_vector_type(8))) short short8;
typedef __attribute__((ext_vector_type(4))) float f32x4;

// ---------------- helpers ----------------
__device__ __forceinline__ u16 f2bf(float f) {
    unsigned int u = __float_as_uint(f);
    u += 0x7fffu + ((u >> 16) & 1u);   // round-to-nearest-even
    return (u16)(u >> 16);
}

__device__ __forceinline__ u32 pack_trunc(float a, float b) {
    return __builtin_amdgcn_perm(__float_as_uint(b), __float_as_uint(a), 0x07060302u);
}

// async global->LDS, 16B per lane. LDS dest = wave-uniform base + lane*16.
__device__ __forceinline__ void gload16(const u16* g, const u16* l) {
    __builtin_amdgcn_global_load_lds(
        (const __attribute__((address_space(1))) unsigned int*)g,
        (__attribute__((address_space(3))) unsigned int*)l, 16, 0, 0);
}

// ---------------- fused cast fp32 -> bf16 (all 7 tensors, one launch) ----------------
__global__ __launch_bounds__(256) void cast_all(const float* __restrict__ k,
                                                const float* __restrict__ q,
                                                const float* __restrict__ v,
                                                const float* __restrict__ wk,
                                                const float* __restrict__ wq,
                                                const float* __restrict__ wv,
                                                const float* __restrict__ wo,
                                                u16* __restrict__ Xk, u16* __restrict__ Xq,
                                                u16* __restrict__ Xv, u16* __restrict__ Wk,
                                                u16* __restrict__ Wq, u16* __restrict__ Wv,
                                                u16* __restrict__ Wo) {
    size_t i = ((size_t)blockIdx.x * 256 + threadIdx.x) * 8;
    const float* src; u16* dst; size_t off;
    if (i < 25165824) {                       // 3 x 2^23 activations
        int r = (int)(i >> 23); off = i & 8388607;
        src = r == 0 ? k : (r == 1 ? q : v);
        dst = r == 0 ? Xk : (r == 1 ? Xq : Xv);
    } else {                                  // 4 x 2^20 weights
        size_t j = i - 25165824;
        int r = (int)(j >> 20); off = j & 1048575;
        src = r == 0 ? wk : (r == 1 ? wq : (r == 2 ? wv : wo));
        dst = r == 0 ? Wk : (r == 1 ? Wq : (r == 2 ? Wv : Wo));
    }
    float4 a = *(const float4*)(src + off);
    float4 b = *(const float4*)(src + off + 4);
    union { u16 h[8]; uint4 u; } r8;
    r8.h[0] = f2bf(a.x); r8.h[1] = f2bf(a.y); r8.h[2] = f2bf(a.z); r8.h[3] = f2bf(a.w);
    r8.h[4] = f2bf(b.x); r8.h[5] = f2bf(b.y); r8.h[6] = f2bf(b.z); r8.h[7] = f2bf(b.w);
    *(uint4*)(dst + off) = r8.u;
}

// =====================================================================================
// v5 GEMM core = round-0 structure (2-phase: sync / stage / sync / compute) with BK=64.
// 128x128 tile, 256 thr (4 waves 2x2), per-wave 64x64 = acc[4][4]; per K-step 32 MFMA.
// LDS 32KB single-buffer. Halves the number of barrier-drain stalls vs BK=32.
//
// Bank swizzle (R2-verified, 0 conflicts): LDS row = 128B = 8 x 16B slots.
// LDS[r][slot] holds global[r][slot ^ (r&7)], staged by pre-permuting the global
// SOURCE column (gload_lds dest is linear); fragment reads use slot (kh*4+quad)^(l16&7)
// -> 16 lanes span all 32 banks, 2-way aliasing = free.
// =====================================================================================

// ---------------- batched QKV GEMM, XCD-swizzled 1-D grid (1536 blocks) ----------------
// flat f: z = f>>9; within z: XCD = i&7 = f&7, j = (f>>3)&7, i-high = (f>>6)&7.
__global__ __launch_bounds__(256) void gemm_qkv(const u16* __restrict__ Xk,
                                                const u16* __restrict__ Xq,
                                                const u16* __restrict__ Xv,
                                                const u16* __restrict__ Wk,
                                                const u16* __restrict__ Wq,
                                                const u16* __restrict__ Wv,
                                                const float* __restrict__ bK,
                                                const float* __restrict__ bQ,
                                                const float* __restrict__ bV,
                                                u16* __restrict__ Kbh,
                                                u16* __restrict__ Qbh,
                                                u16* __restrict__ Vtg,
                                                float kscale) {
    __shared__ u16 sA[128 * 64];
    __shared__ u16 sB[128 * 64];
    const int f = blockIdx.x;
    const int z = f >> 9;
    const int r9 = f & 511;
    const int i_idx = (r9 & 7) | (((r9 >> 6) & 7) << 3);
    const int j_idx = (r9 >> 3) & 7;

    const u16* X = z == 0 ? Xk : (z == 1 ? Xq : Xv);
    const u16* W = z == 0 ? Wk : (z == 1 ? Wq : Wv);
    const float* bias = z == 0 ? bK : (z == 1 ? bQ : bV);
    u16* out = z == 0 ? Kbh : (z == 1 ? Qbh : Vtg);
    const float scale = z == 0 ? kscale : 1.0f;

    const int tid  = threadIdx.x;
    const int wave = tid >> 6, lane = tid & 63;
    const int quad = lane >> 4, l16 = lane & 15;
    const int wm = wave & 1, wn = wave >> 1;
    const int i0 = i_idx * 128, j0 = j_idx * 128;

    // staging: row r = tid>>3 (8 thr/row, 16B each); source col pre-permuted by (r&7)
    const int r = tid >> 3;
    const int sg = (tid & 7) ^ (r & 7);
    const u16* gA = X + (size_t)(i0 + r) * 1024 + sg * 8;
    const u16* gB = W + (size_t)(j0 + r) * 1024 + sg * 8;
    u16* dA = sA + wave * 512;
    u16* dB = sB + wave * 512;
    const int sx = l16 & 7;   // read-side XOR

    f32x4 acc[4][4];
    #pragma unroll
    for (int mt = 0; mt < 4; mt++)
        #pragma unroll
        for (int nt = 0; nt < 4; nt++) acc[mt][nt] = (f32x4){0.f, 0.f, 0.f, 0.f};

    for (int kk = 0; kk < 1024; kk += 64) {
        __syncthreads();
        gload16(gA + kk,         dA);
        gload16(gA + kk + 32768, dA + 2048);
        gload16(gA + kk + 65536, dA + 4096);
        gload16(gA + kk + 98304, dA + 6144);
        gload16(gB + kk,         dB);
        gload16(gB + kk + 32768, dB + 2048);
        gload16(gB + kk + 65536, dB + 4096);
        gload16(gB + kk + 98304, dB + 6144);
        __syncthreads();
        short8 bf[4][2];
        #pragma unroll
        for (int nt = 0; nt < 4; nt++)
            #pragma unroll
            for (int kh = 0; kh < 2; kh++)
                bf[nt][kh] = *(const short8*)&sB[(wn * 64 + nt * 16 + l16) * 64 +
                                                 ((kh * 4 + quad) ^ sx) * 8];
        #pragma unroll
        for (int mt = 0; mt < 4; mt++) {
            const int arow = (wm * 64 + mt * 16 + l16) * 64;
            short8 a0 = *(const short8*)&sA[arow + ((quad) ^ sx) * 8];
            short8 a1 = *(const short8*)&sA[arow + ((4 + quad) ^ sx) * 8];
            #pragma unroll
            for (int nt = 0; nt < 4; nt++) {
                acc[mt][nt] = __builtin_amdgcn_mfma_f32_16x16x32_bf16(a0, bf[nt][0], acc[mt][nt], 0, 0, 0);
                acc[mt][nt] = __builtin_amdgcn_mfma_f32_16x16x32_bf16(a1, bf[nt][1], acc[mt][nt], 0, 0, 0);
            }
        }
    }

    #pragma unroll
    for (int mt = 0; mt < 4; mt++) {
        #pragma unroll
        for (int nt = 0; nt < 4; nt++) {
            int j = j0 + wn * 64 + nt * 16 + l16;
            float bj = bias[j];
            #pragma unroll
            for (int rr = 0; rr < 4; rr++) {
                int i = i0 + wm * 64 + mt * 16 + quad * 4 + rr;
                float v = (acc[mt][nt][rr] + bj) * scale;
                int b = i >> 11, t = i & 2047;
                int h = j >> 6,  dd = j & 63;
                size_t idx;
                if (z == 2) idx = (((size_t)(b * 16 + h)) * 64 + dd) * 2048 + t;
                else        idx = (((size_t)(b * 16 + h)) * 2048 + t) * 64 + dd;
                out[idx] = f2bf(v);
            }
        }
    }
}

// ---------------- output GEMM: 128x64 tile, XCD-swizzled (1024 blocks), BK=64 ---------
// XCD = i&7 = f&7; j = (f>>3)&15; i-high = f>>7.
__global__ __launch_bounds__(256) void gemm_out(const u16* __restrict__ X,
                                                const u16* __restrict__ W,
                                                const float* __restrict__ bias,
                                                float* __restrict__ out) {
    __shared__ u16 sA[128 * 64];
    __shared__ u16 sB[64 * 64];
    const int f = blockIdx.x;
    const int j_idx = (f >> 3) & 15;
    const int i_idx = (f & 7) | ((f >> 7) << 3);
    const int tid  = threadIdx.x;
    const int wave = tid >> 6, lane = tid & 63;
    const int quad = lane >> 4, l16 = lane & 15;
    const int wm = wave & 1, wn = wave >> 1;
    const int i0 = i_idx * 128, j0 = j_idx * 64;

    const int r = tid >> 3;
    const int sg = (tid & 7) ^ (r & 7);
    const u16* gA = X + (size_t)(i0 + r) * 1024 + sg * 8;
    const u16* gB = W + (size_t)(j0 + r) * 1024 + sg * 8;
    u16* dA = sA + wave * 512;
    u16* dB = sB + wave * 512;
    const int sx = l16 & 7;

    f32x4 acc[4][2];
    #pragma unroll
    for (int mt = 0; mt < 4; mt++) {
        acc[mt][0] = (f32x4){0.f, 0.f, 0.f, 0.f};
        acc[mt][1] = (f32x4){0.f, 0.f, 0.f, 0.f};
    }

    for (int kk = 0; kk < 1024; kk += 64) {
        __syncthreads();
        gload16(gA + kk,         dA);
        gload16(gA + kk + 32768, dA + 2048);
        gload16(gA + kk + 65536, dA + 4096);
        gload16(gA + kk + 98304, dA + 6144);
        gload16(gB + kk,         dB);
        gload16(gB + kk + 32768, dB + 2048);
        __syncthreads();
        short8 bf[2][2];
        #pragma unroll
        for (int nt = 0; nt < 2; nt++)
            #pragma unroll
            for (int kh = 0; kh < 2; kh++)
                bf[nt][kh] = *(const short8*)&sB[(wn * 32 + nt * 16 + l16) * 64 +
                                                 ((kh * 4 + quad) ^ sx) * 8];
        #pragma unroll
        for (int mt = 0; mt < 4; mt++) {
            const int arow = (wm * 64 + mt * 16 + l16) * 64;
            short8 a0 = *(const short8*)&sA[arow + ((quad) ^ sx) * 8];
            short8 a1 = *(const short8*)&sA[arow + ((4 + quad) ^ sx) * 8];
            #pragma unroll
            for (int nt = 0; nt < 2; nt++) {
                acc[mt][nt] = __builtin_amdgcn_mfma_f32_16x16x32_bf16(a0, bf[nt][0], acc[mt][nt], 0, 0, 0);
                acc[mt][nt] = __builtin_amdgcn_mfma_f32_16x16x32_bf16(a1, bf[nt][1], acc[mt][nt], 0, 0, 0);
            }
        }
    }

    #pragma unroll
    for (int mt = 0; mt < 4; mt++) {
        #pragma unroll
        for (int nt = 0; nt < 2; nt++) {
            int j = j0 + wn * 32 + nt * 16 + l16;
            float bj = bias[j];
            #pragma unroll
            for (int rr = 0; rr < 4; rr++) {
                int i = i0 + wm * 64 + mt * 16 + quad * 4 + rr;
                out[(size_t)i * 1024 + j] = acc[mt][nt][rr] + bj;
            }
        }
    }
}

// ---------------- flash attention v4 + XCD swizzle (512 blocks) ----------------
#define QST 72   // LDS row stride in u16

__global__ __launch_bounds__(256, 2) void attn_kernel(const u16* __restrict__ Kbh,
                                                      const u16* __restrict__ Qbh,
                                                      const u16* __restrict__ Vtg,
                                                      u16* __restrict__ ctx) {
    __shared__ u16 sQ[64 * QST];             // [s_local][dk]
    __shared__ u16 sVt[64 * QST];            // [dk][s_local]
    __shared__ u16 sP[4 * 2 * 16 * QST];     // [wave][buf][t16][s64]
    const int f = blockIdx.x;
    const int bh = (f & 7) | ((f >> 6) << 3);
    const int tx = (f >> 3) & 7;
    const int tid  = threadIdx.x;
    const int wave = tid >> 6, lane = tid & 63;
    const int quad = lane >> 4, l16 = lane & 15;
    const int t0 = tx * 256;
    const int tw = t0 + wave * 64;
    const size_t base = (size_t)bh * 2048 * 64;

    short8 bk[4][2];
    #pragma unroll
    for (int g = 0; g < 4; g++) {
        const u16* kr = Kbh + base + (size_t)(tw + g * 16 + l16) * 64 + quad * 8;
        bk[g][0] = *(const short8*)kr;
        bk[g][1] = *(const short8*)(kr + 32);
    }
    const short8 ones = {0x3F80, 0x3F80, 0x3F80, 0x3F80, 0x3F80, 0x3F80, 0x3F80, 0x3F80};

    f32x4 accO[4][4];
    #pragma unroll
    for (int g = 0; g < 4; g++)
        #pragma unroll
        for (int dt = 0; dt < 4; dt++) accO[g][dt] = (f32x4){0.f, 0.f, 0.f, 0.f};
    f32x4 accL[4];
    #pragma unroll
    for (int g = 0; g < 4; g++) accL[g] = (f32x4){0.f, 0.f, 0.f, 0.f};

    const int srow = tid >> 2, seg = tid & 3;
    u16* sPw = sP + wave * 2 * 16 * QST;

    for (int s0 = 0; s0 < 2048; s0 += 64) {
        __syncthreads();
        {   // stage Q chunk [s][dk]
            const uint4* gq = (const uint4*)(Qbh + base + (size_t)(s0 + srow) * 64 + seg * 16);
            uint4 q0 = gq[0], q1 = gq[1];
            *(uint4*)&sQ[srow * QST + seg * 16]     = q0;
            *(uint4*)&sQ[srow * QST + seg * 16 + 8] = q1;
        }
        {   // stage V^T chunk [dk][s]
            const uint4* gv = (const uint4*)(Vtg + ((size_t)bh * 64 + srow) * 2048 + s0 + seg * 16);
            uint4 v0 = gv[0], v1 = gv[1];
            *(uint4*)&sVt[srow * QST + seg * 16]     = v0;
            *(uint4*)&sVt[srow * QST + seg * 16 + 8] = v1;
        }
        __syncthreads();

        short8 aq[4][2], av[2][4];
        #pragma unroll
        for (int nt = 0; nt < 4; nt++) {
            aq[nt][0] = *(const short8*)&sQ[(nt * 16 + l16) * QST + quad * 8];
            aq[nt][1] = *(const short8*)&sQ[(nt * 16 + l16) * QST + 32 + quad * 8];
        }
        #pragma unroll
        for (int kk = 0; kk < 2; kk++)
            #pragma unroll
            for (int dt = 0; dt < 4; dt++)
                av[kk][dt] = *(const short8*)&sVt[(dt * 16 + l16) * QST + kk * 32 + quad * 8];

        #pragma unroll
        for (int g = 0; g < 4; g++) {
            f32x4 aS[4];
            #pragma unroll
            for (int nt = 0; nt < 4; nt++) {
                f32x4 s = __builtin_amdgcn_mfma_f32_16x16x32_bf16(aq[nt][0], bk[g][0],
                            (f32x4){0.f, 0.f, 0.f, 0.f}, 0, 0, 0);
                aS[nt] = __builtin_amdgcn_mfma_f32_16x16x32_bf16(aq[nt][1], bk[g][1], s, 0, 0, 0);
            }
            u16* pb = sPw + (g & 1) * 16 * QST;
            #pragma unroll
            for (int nt = 0; nt < 4; nt++) {
                float p0 = __builtin_amdgcn_exp2f(aS[nt][0]);
                float p1 = __builtin_amdgcn_exp2f(aS[nt][1]);
                float p2 = __builtin_amdgcn_exp2f(aS[nt][2]);
                float p3 = __builtin_amdgcn_exp2f(aS[nt][3]);
                uint2 pk = { pack_trunc(p0, p1), pack_trunc(p2, p3) };
                *(uint2*)&pb[l16 * QST + nt * 16 + quad * 4] = pk;
            }
            #pragma unroll
            for (int kk = 0; kk < 2; kk++) {
                short8 bp = *(const short8*)&pb[l16 * QST + kk * 32 + quad * 8];
                accL[g] = __builtin_amdgcn_mfma_f32_16x16x32_bf16(ones, bp, accL[g], 0, 0, 0);
                #pragma unroll
                for (int dt = 0; dt < 4; dt++)
                    accO[g][dt] = __builtin_amdgcn_mfma_f32_16x16x32_bf16(av[kk][dt], bp, accO[g][dt], 0, 0, 0);
            }
        }
    }

    const int b = bh >> 4, h = bh & 15;
    #pragma unroll
    for (int g = 0; g < 4; g++) {
        float inv = 1.f / accL[g][0];
        int t = tw + g * 16 + l16;
        u16* orow = ctx + ((size_t)(b * 2048 + t)) * 1024 + h * 64;
        #pragma unroll
        for (int dt = 0; dt < 4; dt++) {
            union { u16 h4[4]; uint2 u; } o;
            #pragma unroll
            for (int rr = 0; rr < 4; rr++) o.h4[rr] = f2bf(accO[g][dt][rr] * inv);
            *(uint2*)&orow[dt * 16 + quad * 4] = o.u;
        }
    }
}

// ---------------- launcher ----------------
extern "C" void kernel_launch(void* const* d_in, const int* in_sizes, int n_in,
                              void* d_out, int out_size, void* d_ws, size_t ws_size,
                              hipStream_t stream) {
    const float* keys    = (const float*)d_in[0];
    const float* queries = (const float*)d_in[1];
    const float* values  = (const float*)d_in[2];
    // d_in[3] = pad_mask (unused by the reference, faithfully ignored)
    const float* WKb = (const float*)d_in[5];
    const float* WQb = (const float*)d_in[7];
    const float* WVb = (const float*)d_in[9];
    const float* WOb = (const float*)d_in[11];

    char* ws = (char*)d_ws;
    const size_t MB = 1 << 20;
    u16* Kbh = (u16*)(ws + 0 * MB);
    u16* Qbh = (u16*)(ws + 16 * MB);
    u16* Vtg = (u16*)(ws + 32 * MB);
    u16* Xk  = (u16*)(ws + 48 * MB);
    u16* Xq  = (u16*)(ws + 64 * MB);
    u16* Xv  = (u16*)(ws + 80 * MB);
    u16* Wk  = (u16*)(ws + 96 * MB);
    u16* Wq  = (u16*)(ws + 98 * MB);
    u16* Wv  = (u16*)(ws + 100 * MB);
    u16* Wo  = (u16*)(ws + 102 * MB);
    u16* ctx = (u16*)(ws + 48 * MB);   // aliases Xk (dead after QKV projection)

    cast_all<<<14336, 256, 0, stream>>>(keys, queries, values,
                                        (const float*)d_in[4], (const float*)d_in[6],
                                        (const float*)d_in[8], (const float*)d_in[10],
                                        Xk, Xq, Xv, Wk, Wq, Wv, Wo);

    const float kscale = 1.4426950408889634f * 0.125f;  // log2(e)/sqrt(d_key)
    gemm_qkv<<<1536, 256, 0, stream>>>(Xk, Xq, Xv, Wk, Wq, Wv,
                                       WKb, WQb, WVb, Kbh, Qbh, Vtg, kscale);

    attn_kernel<<<512, 256, 0, stream>>>(Kbh, Qbh, Vtg, ctx);

    gemm_out<<<1024, 256, 0, stream>>>(ctx, Wo, WOb, (float*)d_out);
}